// Round 11
// baseline (212.097 us; speedup 1.0000x reference)
//
#include <hip/hip_runtime.h>
#include <stdint.h>

// ImplicitRHMCSampler — fused single-kernel implementation for MI355X (gfx950).
//
// Round-10 fix: with extern __shared__, the backend sees 0 LDS and targets
// 8 waves/EU -> 64 VGPRs -> spills (rounds 8-10, ~340 MB scratch, 210 us).
// Static __shared__ of the full 160 KB makes the occupancy bound visible:
// 1 block/CU = 16 waves = 4 waves/EU -> VGPR target 512/4 = 128. Address
// arrays folded (aS = aW + 65536, aB = aW + dB) to keep live set ~95 < 128.
//
// Structure (unchanged since round 7): wave-QUAD shares a 16-row state tile;
// each wave owns a quarter of the n-columns (4 of 16 MFMA n-tiles).
//  * grid 256 x 1024 threads; 1 block/CU (160 KB LDS), 16 waves, 4 groups.
//  * W (row-major) and W^T in LDS as fp8 e4m3, XOR-swizzled per row&15.
//  * Ping-pong 16x256 fp8 state buffer per group; ONE __syncthreads per
//    phase orders partner-wave writes before full-k MFMA reads.
//  * v_mfma_f32_16x16x32_fp8_fp8, transposed orientation (D = Wcopy@state^T).
//  * 6 MFMA-matmul phases per leapfrog step + 1 initial = 37 total.

typedef float floatx4 __attribute__((ext_vector_type(4)));

#define LDS_WRM   0        // W row-major, fp8, 64 KB
#define LDS_S     65536    // W^T row-major, fp8, 64 KB
#define LDS_STATE 131072   // + group*8192 + parity*4096 : 16x256 fp8
#define LDS_TOTAL 163840   // exactly 160 KiB

#define L2E 1.4426950408889634f
#define LN2 0.6931471805599453f

// gfx950: __builtin_amdgcn_logf computes log2 (see __clang_hip_math.h __log2f)
#define LOG2F(x) __builtin_amdgcn_logf(x)
#define EXP2F(x) __builtin_amdgcn_exp2f(x)
#define RCPF(x)  __builtin_amdgcn_rcpf(x)

__device__ __forceinline__ uint32_t pkbf16(float a, float b) {
  uint32_t r;
  asm("v_cvt_pk_bf16_f32 %0, %1, %2" : "=v"(r) : "v"(a), "v"(b));
  return r;
}

// acc[nt] = (Wcopy @ state^T) tile slice for this wave's 4 n-tiles.
// AOFF = 0 (W row-major) or 65536 (W^T copy); PB = state parity (const).
// B-frag address = aW[kc] + dB + PB*4096 (dB maps the W-address to the
// group's state buffer; same colb+c8 swizzle applies).
#define MM(AOFF, PB)                                                           \
  do {                                                                         \
    _Pragma("unroll") for (int kc_ = 0; kc_ < 8; ++kc_) {                      \
      long long bfrag_ = *reinterpret_cast<const long long*>(                  \
          smem + aW[kc_] + dB + (PB) * 4096);                                  \
      _Pragma("unroll") for (int nt_ = 0; nt_ < 4; ++nt_) {                    \
        long long afrag_ = *reinterpret_cast<const long long*>(                \
            smem + aW[kc_] + (AOFF) + nt_ * 4096);                             \
        acc[nt_] = __builtin_amdgcn_mfma_f32_16x16x32_fp8_fp8(                 \
            afrag_, bfrag_, kc_ ? acc[nt_] : ZERO4, 0, 0, 0);                  \
      }                                                                        \
    }                                                                          \
  } while (0)

__global__ void __launch_bounds__(1024, 1)
rhmc_kernel(const float* __restrict__ z0, const float* __restrict__ v0,
            const float* __restrict__ Wg, const float* __restrict__ biasg,
            float* __restrict__ out) {
  __shared__ char smem[LDS_TOTAL];  // static: makes 1-block/CU visible
  const floatx4 ZERO4 = {0.f, 0.f, 0.f, 0.f};
  const int tid = threadIdx.x;
  const int blk = blockIdx.x;

  // ---- stage W row-major -> LDS fp8 (swizzled) ----
#pragma unroll 1
  for (int it = 0; it < 8; ++it) {
    int chunk = tid + it * 1024;  // 8192 chunks of 8 elements
    int row = chunk >> 5;
    int c8 = chunk & 31;
    const float4* p = reinterpret_cast<const float4*>(Wg + row * 256 + c8 * 8);
    float4 x0 = p[0], x1 = p[1];
    int lo = __builtin_amdgcn_cvt_pk_fp8_f32(x0.x, x0.y, 0, false);
    lo = __builtin_amdgcn_cvt_pk_fp8_f32(x0.z, x0.w, lo, true);
    int hi = __builtin_amdgcn_cvt_pk_fp8_f32(x1.x, x1.y, 0, false);
    hi = __builtin_amdgcn_cvt_pk_fp8_f32(x1.z, x1.w, hi, true);
    int sw = (c8 ^ (row & 15)) << 3;
    *reinterpret_cast<int2*>(smem + LDS_WRM + row * 256 + sw) =
        make_int2(lo, hi);
  }
  // ---- stage S = W^T -> LDS fp8 (swizzled); column gather (L2-hot) ----
#pragma unroll 1
  for (int it = 0; it < 8; ++it) {
    int chunk = tid + it * 1024;
    int n = chunk >> 5;
    int c8 = chunk & 31;
    float xs[8];
#pragma unroll
    for (int j = 0; j < 8; ++j) xs[j] = Wg[(c8 * 8 + j) * 256 + n];
    int lo = __builtin_amdgcn_cvt_pk_fp8_f32(xs[0], xs[1], 0, false);
    lo = __builtin_amdgcn_cvt_pk_fp8_f32(xs[2], xs[3], lo, true);
    int hi = __builtin_amdgcn_cvt_pk_fp8_f32(xs[4], xs[5], 0, false);
    hi = __builtin_amdgcn_cvt_pk_fp8_f32(xs[6], xs[7], hi, true);
    int sw = (c8 ^ (n & 15)) << 3;
    *reinterpret_cast<int2*>(smem + LDS_S + n * 256 + sw) = make_int2(lo, hi);
  }
  __syncthreads();

  const int lane = tid & 63;
  const int wv = tid >> 6;
  const int gp = wv >> 2;   // group of 4 waves sharing 16 rows
  const int nq = wv & 3;    // n-quarter owned by this wave
  const int l15 = lane & 15;
  const int g = lane >> 4;
  const int colb = l15 * 256;
  const int stateB = LDS_STATE + gp * 8192;  // parity added as const offset
  const int m = blk * 64 + gp * 16 + l15;    // global batch row of this lane

  // per-kc fragment addresses (swizzle folded in once); aS = aW + 65536,
  // aB = aW + dB.
  int aW[8];
  const int dB = LDS_STATE + gp * 8192 - nq * 16384;
#pragma unroll
  for (int kc = 0; kc < 8; ++kc) {
    int c8 = (((4 * kc + g) ^ l15) << 3);
    aW[kc] = LDS_WRM + nq * 16384 + colb + c8;
  }
  // state write addresses: lane writes 4 fp8 at n = 16*(4nq+t)+4g, r=0..3
  int ws[4];
#pragma unroll
  for (int t = 0; t < 4; ++t)
    ws[t] = stateB + colb +
            ((((8 * nq + 2 * t + (g >> 1)) ^ l15)) << 3) + (g & 1) * 4;

  // ---- load state: lane owns row m, n = 64*nq + 16t + 4g + r ----
  float z_[16], v_[16];
  {
    const float4* zr =
        reinterpret_cast<const float4*>(z0 + m * 256 + nq * 64 + g * 4);
    const float4* vr =
        reinterpret_cast<const float4*>(v0 + m * 256 + nq * 64 + g * 4);
#pragma unroll
    for (int t = 0; t < 4; ++t) {
      float4 a = zr[t * 4];
      float4 b = vr[t * 4];
      z_[t * 4 + 0] = a.x; z_[t * 4 + 1] = a.y;
      z_[t * 4 + 2] = a.z; z_[t * 4 + 3] = a.w;
      v_[t * 4 + 0] = b.x; v_[t * 4 + 1] = b.y;
      v_[t * 4 + 2] = b.z; v_[t * 4 + 3] = b.w;
    }
  }
  uint32_t bias_[8];
#pragma unroll
  for (int t = 0; t < 4; ++t) {
    const float* bp = biasg + (4 * nq + t) * 16 + g * 4;
    bias_[t * 2 + 0] = pkbf16(bp[0], bp[1]);
    bias_[t * 2 + 1] = pkbf16(bp[2], bp[3]);
  }

  floatx4 acc[4];
  uint32_t pq_[16];   // packed bf16 (p = 0.5*sig(a), q = p/sp(a)) per element
  uint32_t spa_[8];   // packed bf16 softplus(a) pairs
  uint32_t k0_[8];    // packed bf16 z-loop constant pairs

  // quantize + write this wave's 16 values (its n-quarter of the tile)
  auto writeState = [&](auto val, int PB) {
#pragma unroll
    for (int t = 0; t < 4; ++t) {
      int d = __builtin_amdgcn_cvt_pk_fp8_f32(val(t * 4 + 0), val(t * 4 + 1),
                                              0, false);
      d = __builtin_amdgcn_cvt_pk_fp8_f32(val(t * 4 + 2), val(t * 4 + 3), d,
                                          true);
      *reinterpret_cast<int*>(smem + ws[t] + PB * 4096) = d;
    }
  };
  // from acc = z@W (pre-bias): p, q, sp(a)
  auto stats = [&]() {
#pragma unroll
    for (int nt = 0; nt < 4; ++nt) {
#pragma unroll
      for (int rr = 0; rr < 2; ++rr) {
        uint32_t bp = bias_[nt * 2 + rr];
        float sp2[2];
#pragma unroll
        for (int h = 0; h < 2; ++h) {
          float b = __uint_as_float(h ? (bp & 0xffff0000u) : (bp << 16));
          float a = acc[nt][rr * 2 + h] + b;
          float e = EXP2F(a * L2E);
          float onep = 1.0f + e;
          float r1 = RCPF(onep);
          float p = 0.5f * e * r1;
          float sp = LOG2F(onep) * LN2;
          sp = fmaxf(sp, 1e-12f);
          float q = p * RCPF(sp);
          pq_[nt * 4 + rr * 2 + h] = pkbf16(p, q);
          sp2[h] = sp;
        }
        spa_[nt * 2 + rr] = pkbf16(sp2[0], sp2[1]);
      }
    }
  };
  // u = p*vh^2 - q  (dH_dz integrand)
  auto uVal = [&](int e) {
    uint32_t pk = pq_[e];
    float p = __uint_as_float(pk << 16);
    float q = __uint_as_float(pk & 0xffff0000u);
    float vv = v_[e];
    return fmaf(p * vv, vv, -q);
  };

  // ---- initial stats at z0 (parity 0) ----
  writeState([&](int e) { return z_[e]; }, 0);
  __syncthreads();
  MM(LDS_S, 0);
  stats();

#pragma unroll 1
  for (int step = 0; step < 6; ++step) {
    // A (parity 1): v-loop collapsed: vh = v - 8*(gamma/2)*dH_dz(z, v)
    writeState(uVal, 1);
    __syncthreads();
    MM(0, 1);
#pragma unroll
    for (int nt = 0; nt < 4; ++nt)
#pragma unroll
      for (int r = 0; r < 4; ++r) v_[nt * 4 + r] -= 0.04f * acc[nt][r];

    // B (parity 0): c = vh@W + bias -> w = 0.5*sigma(c)/sp(c)
    writeState([&](int e) { return v_[e]; }, 0);
    __syncthreads();
    MM(LDS_S, 0);
    // B' (parity 1): acc -> w, then r = w @ W^T
    writeState(
        [&](int e) {
          int nt = e >> 2, r = e & 3;
          uint32_t bp = bias_[nt * 2 + (r >> 1)];
          float b = __uint_as_float((r & 1) ? (bp & 0xffff0000u) : (bp << 16));
          float c = acc[nt][r] + b;
          float ee = EXP2F(c * L2E);
          float onep = 1.0f + ee;
          float sp = LOG2F(onep) * LN2;
          return 0.5f * ee * RCPF(onep * sp);
        },
        1);
    __syncthreads();
    MM(0, 1);

    // B2: first half of z-loop (frozen at a(z)): zn4 = z + 0.04*g0,
    //     k0 = 0.02*(g0 - r) with g0 = sp(a)*vh - r
#pragma unroll
    for (int nt = 0; nt < 4; ++nt)
#pragma unroll
      for (int rr = 0; rr < 2; ++rr) {
        uint32_t sppk = spa_[nt * 2 + rr];
        float k0h[2];
#pragma unroll
        for (int h = 0; h < 2; ++h) {
          int e = nt * 4 + rr * 2 + h;
          float sp = __uint_as_float(h ? (sppk & 0xffff0000u) : (sppk << 16));
          float A = sp * v_[e];
          float rv = acc[nt][rr * 2 + h];
          z_[e] += 0.04f * (A - rv);
          k0h[h] = 0.02f * (A - 2.0f * rv);
        }
        k0_[nt * 2 + rr] = pkbf16(k0h[0], k0h[1]);
      }

    // C1 (parity 0): midpoint refresh a(zn4); zn8 = zn4 + k0 + 0.02*sp*vh
    writeState([&](int e) { return z_[e]; }, 0);
    __syncthreads();
    MM(LDS_S, 0);
#pragma unroll
    for (int nt = 0; nt < 4; ++nt)
#pragma unroll
      for (int rr = 0; rr < 2; ++rr) {
        uint32_t bp = bias_[nt * 2 + rr];
        uint32_t kk = k0_[nt * 2 + rr];
#pragma unroll
        for (int h = 0; h < 2; ++h) {
          int e = nt * 4 + rr * 2 + h;
          float b = __uint_as_float(h ? (bp & 0xffff0000u) : (bp << 16));
          float a = acc[nt][rr * 2 + h] + b;
          float ee = EXP2F(a * L2E);
          float sp = LOG2F(1.0f + ee) * LN2;
          float k0v = __uint_as_float(h ? (kk & 0xffff0000u) : (kk << 16));
          z_[e] += k0v + 0.02f * sp * v_[e];
        }
      }

    // D (parity 1): a(z_new) -> stats (also serves next step's entry)
    writeState([&](int e) { return z_[e]; }, 1);
    __syncthreads();
    MM(LDS_S, 1);
    stats();

    // E (parity 0): v_new = vh - (gamma/2)*dH_dz(z_new, vh)
    writeState(uVal, 0);
    __syncthreads();
    MM(0, 0);
#pragma unroll
    for (int nt = 0; nt < 4; ++nt)
#pragma unroll
      for (int r = 0; r < 4; ++r) v_[nt * 4 + r] -= 0.005f * acc[nt][r];
  }

  // ---- store (2, 16384, 256) fp32 ----
  float4* oz =
      reinterpret_cast<float4*>(out + m * 256 + nq * 64 + g * 4);
  float4* ov = reinterpret_cast<float4*>(out + 16384 * 256 + m * 256 +
                                         nq * 64 + g * 4);
#pragma unroll
  for (int t = 0; t < 4; ++t) {
    float4 a, b;
    a.x = z_[t * 4 + 0]; a.y = z_[t * 4 + 1];
    a.z = z_[t * 4 + 2]; a.w = z_[t * 4 + 3];
    b.x = v_[t * 4 + 0]; b.y = v_[t * 4 + 1];
    b.z = v_[t * 4 + 2]; b.w = v_[t * 4 + 3];
    oz[t * 4] = a;
    ov[t * 4] = b;
  }
}

extern "C" void kernel_launch(void* const* d_in, const int* in_sizes, int n_in,
                              void* d_out, int out_size, void* d_ws,
                              size_t ws_size, hipStream_t stream) {
  (void)in_sizes; (void)n_in; (void)d_ws; (void)ws_size; (void)out_size;
  const float* z0 = (const float*)d_in[0];
  const float* v0 = (const float*)d_in[1];
  const float* Wg = (const float*)d_in[2];
  const float* bg = (const float*)d_in[3];
  float* out = (float*)d_out;
  rhmc_kernel<<<256, 1024, 0, stream>>>(z0, v0, Wg, bg, out);
}

// Round 12
// 128.079 us; speedup vs baseline: 1.6560x; 1.6560x over previous
//
#include <hip/hip_runtime.h>
#include <stdint.h>

// ImplicitRHMCSampler — fused single-kernel implementation for MI355X (gfx950).
//
// Round-11 model update: the unified VGPR file is 512 regs per SIMD wave-slot
// budget; a 1024-thread block forces 4 waves/SIMD -> hard 128-reg budget ->
// unavoidable spills (rounds 8-11, 210 us). Revert to 512 threads
// (2 waves/SIMD, 256-reg budget, spill-free per round 7) and win back latency
// via ILP instead of occupancy:
//  * 8 waves = 2 groups x 4 waves; group owns 32 rows as TWO 16-row subtiles
//    (mt=0,1). Per wave: 4 n-tiles x 2 subtiles = 64 MFMA/phase (same work as
//    round 7) but two independent B-frag dependency chains.
//  * S-copy A-fragments for kc<4 hoisted to registers once (32 VGPR):
//    S-phase LDS reads 72 -> 32 b64; W-phase 72 -> 48 (A shared across mt).
//  * W / W^T fp8 in LDS, XOR-swizzled (unchanged). Ping-pong state per group:
//    gp*16384 + parity*8192 + mt*4096. LDS exactly 160 KiB.
//  * v_mfma_f32_16x16x32_fp8_fp8; 6 MFMA phases/leapfrog step + init = 37.

typedef float floatx4 __attribute__((ext_vector_type(4)));

#define LDS_WRM   0        // W row-major, fp8, 64 KB
#define LDS_S     65536    // W^T row-major, fp8, 64 KB
#define LDS_STATE 131072   // + gp*16384 + parity*8192 + mt*4096
#define LDS_TOTAL 163840   // exactly 160 KiB

#define L2E 1.4426950408889634f
#define LN2 0.6931471805599453f

// gfx950: __builtin_amdgcn_logf computes log2 (see __clang_hip_math.h __log2f)
#define LOG2F(x) __builtin_amdgcn_logf(x)
#define EXP2F(x) __builtin_amdgcn_exp2f(x)
#define RCPF(x)  __builtin_amdgcn_rcpf(x)

__device__ __forceinline__ uint32_t pkbf16(float a, float b) {
  uint32_t r;
  asm("v_cvt_pk_bf16_f32 %0, %1, %2" : "=v"(r) : "v"(a), "v"(b));
  return r;
}

// acc[mt][nt] += A(kc) x state_mt(kc)^T. AEXPR supplies the A-fragment.
#define MM(AEXPR, PB)                                                         \
  do {                                                                        \
    _Pragma("unroll") for (int kc_ = 0; kc_ < 8; ++kc_) {                     \
      const char* bb_ = smem + aW[kc_] + dB + (PB) * 8192;                    \
      long long bf0_ = *reinterpret_cast<const long long*>(bb_);              \
      long long bf1_ = *reinterpret_cast<const long long*>(bb_ + 4096);       \
      _Pragma("unroll") for (int nt_ = 0; nt_ < 4; ++nt_) {                   \
        long long af_ = (AEXPR);                                              \
        acc[0][nt_] = __builtin_amdgcn_mfma_f32_16x16x32_fp8_fp8(             \
            af_, bf0_, kc_ ? acc[0][nt_] : ZERO4, 0, 0, 0);                   \
        acc[1][nt_] = __builtin_amdgcn_mfma_f32_16x16x32_fp8_fp8(             \
            af_, bf1_, kc_ ? acc[1][nt_] : ZERO4, 0, 0, 0);                   \
      }                                                                       \
    }                                                                         \
  } while (0)

#define AEXPR_W                                                               \
  (*reinterpret_cast<const long long*>(smem + aW[kc_] + nt_ * 4096))
#define AEXPR_S                                                               \
  (kc_ < 4 ? sfrag[nt_][kc_ & 3]                                              \
           : *reinterpret_cast<const long long*>(smem + aW[kc_] + 65536 +     \
                                                 nt_ * 4096))

__global__ void __launch_bounds__(512, 1)
rhmc_kernel(const float* __restrict__ z0, const float* __restrict__ v0,
            const float* __restrict__ Wg, const float* __restrict__ biasg,
            float* __restrict__ out) {
  __shared__ char smem[LDS_TOTAL];
  const floatx4 ZERO4 = {0.f, 0.f, 0.f, 0.f};
  const int tid = threadIdx.x;
  const int blk = blockIdx.x;

  // ---- stage W row-major -> LDS fp8 (swizzled) ----
#pragma unroll 1
  for (int it = 0; it < 16; ++it) {
    int chunk = tid + it * 512;  // 8192 chunks of 8 elements
    int row = chunk >> 5;
    int c8 = chunk & 31;
    const float4* p = reinterpret_cast<const float4*>(Wg + row * 256 + c8 * 8);
    float4 x0 = p[0], x1 = p[1];
    int lo = __builtin_amdgcn_cvt_pk_fp8_f32(x0.x, x0.y, 0, false);
    lo = __builtin_amdgcn_cvt_pk_fp8_f32(x0.z, x0.w, lo, true);
    int hi = __builtin_amdgcn_cvt_pk_fp8_f32(x1.x, x1.y, 0, false);
    hi = __builtin_amdgcn_cvt_pk_fp8_f32(x1.z, x1.w, hi, true);
    int sw = (c8 ^ (row & 15)) << 3;
    *reinterpret_cast<int2*>(smem + LDS_WRM + row * 256 + sw) =
        make_int2(lo, hi);
  }
  // ---- stage S = W^T -> LDS fp8 (swizzled); column gather (L2-hot) ----
#pragma unroll 1
  for (int it = 0; it < 16; ++it) {
    int chunk = tid + it * 512;
    int n = chunk >> 5;
    int c8 = chunk & 31;
    float xs[8];
#pragma unroll
    for (int j = 0; j < 8; ++j) xs[j] = Wg[(c8 * 8 + j) * 256 + n];
    int lo = __builtin_amdgcn_cvt_pk_fp8_f32(xs[0], xs[1], 0, false);
    lo = __builtin_amdgcn_cvt_pk_fp8_f32(xs[2], xs[3], lo, true);
    int hi = __builtin_amdgcn_cvt_pk_fp8_f32(xs[4], xs[5], 0, false);
    hi = __builtin_amdgcn_cvt_pk_fp8_f32(xs[6], xs[7], hi, true);
    int sw = (c8 ^ (n & 15)) << 3;
    *reinterpret_cast<int2*>(smem + LDS_S + n * 256 + sw) = make_int2(lo, hi);
  }
  __syncthreads();

  const int lane = tid & 63;
  const int wv = tid >> 6;
  const int gp = wv >> 2;   // group of 4 waves sharing 32 rows
  const int nq = wv & 3;    // n-quarter owned by this wave
  const int l15 = lane & 15;
  const int g = lane >> 4;
  const int colb = l15 * 256;
  const int stateB = LDS_STATE + gp * 16384;  // + parity*8192 + mt*4096
  const int mrow = blk * 64 + gp * 32 + l15;  // batch row (mt=0 subtile)

  // per-kc fragment addresses (swizzle folded in once); aS = aW + 65536,
  // aB = aW + dB (+ mt*4096 + parity*8192).
  int aW[8];
  const int dB = stateB - nq * 16384;
#pragma unroll
  for (int kc = 0; kc < 8; ++kc) {
    int c8 = (((4 * kc + g) ^ l15) << 3);
    aW[kc] = LDS_WRM + nq * 16384 + colb + c8;
  }
  // state write addresses: lane writes 4 fp8 at n = 16*(4nq+t)+4g, r=0..3
  int ws[4];
#pragma unroll
  for (int t = 0; t < 4; ++t)
    ws[t] = stateB + colb +
            ((((8 * nq + 2 * t + (g >> 1)) ^ l15)) << 3) + (g & 1) * 4;

  // hoist S-copy A-fragments for kc<4 (32 VGPR, read once)
  long long sfrag[4][4];
#pragma unroll
  for (int nt = 0; nt < 4; ++nt)
#pragma unroll
    for (int kc = 0; kc < 4; ++kc)
      sfrag[nt][kc] = *reinterpret_cast<const long long*>(smem + aW[kc] +
                                                          65536 + nt * 4096);

  // ---- load state: lane owns rows mrow+16*mt, n = 64*nq + 16t + 4g + r ----
  float z_[2][16], v_[2][16];
#pragma unroll
  for (int mt = 0; mt < 2; ++mt) {
    const float4* zr = reinterpret_cast<const float4*>(
        z0 + (mrow + mt * 16) * 256 + nq * 64 + g * 4);
    const float4* vr = reinterpret_cast<const float4*>(
        v0 + (mrow + mt * 16) * 256 + nq * 64 + g * 4);
#pragma unroll
    for (int t = 0; t < 4; ++t) {
      float4 a = zr[t * 4];
      float4 b = vr[t * 4];
      z_[mt][t * 4 + 0] = a.x; z_[mt][t * 4 + 1] = a.y;
      z_[mt][t * 4 + 2] = a.z; z_[mt][t * 4 + 3] = a.w;
      v_[mt][t * 4 + 0] = b.x; v_[mt][t * 4 + 1] = b.y;
      v_[mt][t * 4 + 2] = b.z; v_[mt][t * 4 + 3] = b.w;
    }
  }
  uint32_t bias_[8];  // shared across mt (depends only on n)
#pragma unroll
  for (int t = 0; t < 4; ++t) {
    const float* bp = biasg + (4 * nq + t) * 16 + g * 4;
    bias_[t * 2 + 0] = pkbf16(bp[0], bp[1]);
    bias_[t * 2 + 1] = pkbf16(bp[2], bp[3]);
  }

  floatx4 acc[2][4];
  uint32_t pq_[2][16];  // packed bf16 (p = 0.5*sig(a), q = p/sp(a))
  uint32_t spa_[2][8];  // packed bf16 softplus(a) pairs
  uint32_t k0_[2][8];   // packed bf16 z-loop constant pairs

  // quantize + write this wave's 2x16 values (n-quarter of both subtiles)
  auto writeState = [&](auto val, int PB) {
#pragma unroll
    for (int mt = 0; mt < 2; ++mt)
#pragma unroll
      for (int t = 0; t < 4; ++t) {
        int d = __builtin_amdgcn_cvt_pk_fp8_f32(val(mt, t * 4 + 0),
                                                val(mt, t * 4 + 1), 0, false);
        d = __builtin_amdgcn_cvt_pk_fp8_f32(val(mt, t * 4 + 2),
                                            val(mt, t * 4 + 3), d, true);
        *reinterpret_cast<int*>(smem + ws[t] + mt * 4096 + PB * 8192) = d;
      }
  };
  // from acc = z@W (pre-bias): p, q, sp(a)
  auto stats = [&]() {
#pragma unroll
    for (int mt = 0; mt < 2; ++mt)
#pragma unroll
      for (int nt = 0; nt < 4; ++nt)
#pragma unroll
        for (int rr = 0; rr < 2; ++rr) {
          uint32_t bp = bias_[nt * 2 + rr];
          float sp2[2];
#pragma unroll
          for (int h = 0; h < 2; ++h) {
            float b = __uint_as_float(h ? (bp & 0xffff0000u) : (bp << 16));
            float a = acc[mt][nt][rr * 2 + h] + b;
            float e = EXP2F(a * L2E);
            float onep = 1.0f + e;
            float r1 = RCPF(onep);
            float p = 0.5f * e * r1;
            float sp = LOG2F(onep) * LN2;
            sp = fmaxf(sp, 1e-12f);
            float q = p * RCPF(sp);
            pq_[mt][nt * 4 + rr * 2 + h] = pkbf16(p, q);
            sp2[h] = sp;
          }
          spa_[mt][nt * 2 + rr] = pkbf16(sp2[0], sp2[1]);
        }
  };
  // u = p*vh^2 - q  (dH_dz integrand)
  auto uVal = [&](int mt, int e) {
    uint32_t pk = pq_[mt][e];
    float p = __uint_as_float(pk << 16);
    float q = __uint_as_float(pk & 0xffff0000u);
    float vv = v_[mt][e];
    return fmaf(p * vv, vv, -q);
  };

  // ---- initial stats at z0 (parity 0) ----
  writeState([&](int mt, int e) { return z_[mt][e]; }, 0);
  __syncthreads();
  MM(AEXPR_S, 0);
  stats();

#pragma unroll 1
  for (int step = 0; step < 6; ++step) {
    // A (parity 1): v-loop collapsed: vh = v - 8*(gamma/2)*dH_dz(z, v)
    writeState(uVal, 1);
    __syncthreads();
    MM(AEXPR_W, 1);
#pragma unroll
    for (int mt = 0; mt < 2; ++mt)
#pragma unroll
      for (int nt = 0; nt < 4; ++nt)
#pragma unroll
        for (int r = 0; r < 4; ++r)
          v_[mt][nt * 4 + r] -= 0.04f * acc[mt][nt][r];

    // B (parity 0): c = vh@W + bias -> w = 0.5*sigma(c)/sp(c)
    writeState([&](int mt, int e) { return v_[mt][e]; }, 0);
    __syncthreads();
    MM(AEXPR_S, 0);
    // B' (parity 1): acc -> w, then r = w @ W^T
    writeState(
        [&](int mt, int e) {
          int nt = e >> 2, r = e & 3;
          uint32_t bp = bias_[nt * 2 + (r >> 1)];
          float b = __uint_as_float((r & 1) ? (bp & 0xffff0000u) : (bp << 16));
          float c = acc[mt][nt][r] + b;
          float ee = EXP2F(c * L2E);
          float onep = 1.0f + ee;
          float sp = LOG2F(onep) * LN2;
          return 0.5f * ee * RCPF(onep * sp);
        },
        1);
    __syncthreads();
    MM(AEXPR_W, 1);

    // B2: first half of z-loop (frozen at a(z)): zn4 = z + 0.04*g0,
    //     k0 = 0.02*(g0 - r) with g0 = sp(a)*vh - r
#pragma unroll
    for (int mt = 0; mt < 2; ++mt)
#pragma unroll
      for (int nt = 0; nt < 4; ++nt)
#pragma unroll
        for (int rr = 0; rr < 2; ++rr) {
          uint32_t sppk = spa_[mt][nt * 2 + rr];
          float k0h[2];
#pragma unroll
          for (int h = 0; h < 2; ++h) {
            int e = nt * 4 + rr * 2 + h;
            float sp =
                __uint_as_float(h ? (sppk & 0xffff0000u) : (sppk << 16));
            float A = sp * v_[mt][e];
            float rv = acc[mt][nt][rr * 2 + h];
            z_[mt][e] += 0.04f * (A - rv);
            k0h[h] = 0.02f * (A - 2.0f * rv);
          }
          k0_[mt][nt * 2 + rr] = pkbf16(k0h[0], k0h[1]);
        }

    // C1 (parity 0): midpoint refresh a(zn4); zn8 = zn4 + k0 + 0.02*sp*vh
    writeState([&](int mt, int e) { return z_[mt][e]; }, 0);
    __syncthreads();
    MM(AEXPR_S, 0);
#pragma unroll
    for (int mt = 0; mt < 2; ++mt)
#pragma unroll
      for (int nt = 0; nt < 4; ++nt)
#pragma unroll
        for (int rr = 0; rr < 2; ++rr) {
          uint32_t bp = bias_[nt * 2 + rr];
          uint32_t kk = k0_[mt][nt * 2 + rr];
#pragma unroll
          for (int h = 0; h < 2; ++h) {
            int e = nt * 4 + rr * 2 + h;
            float b = __uint_as_float(h ? (bp & 0xffff0000u) : (bp << 16));
            float a = acc[mt][nt][rr * 2 + h] + b;
            float ee = EXP2F(a * L2E);
            float sp = LOG2F(1.0f + ee) * LN2;
            float k0v = __uint_as_float(h ? (kk & 0xffff0000u) : (kk << 16));
            z_[mt][e] += k0v + 0.02f * sp * v_[mt][e];
          }
        }

    // D (parity 1): a(z_new) -> stats (also serves next step's entry)
    writeState([&](int mt, int e) { return z_[mt][e]; }, 1);
    __syncthreads();
    MM(AEXPR_S, 1);
    stats();

    // E (parity 0): v_new = vh - (gamma/2)*dH_dz(z_new, vh)
    writeState(uVal, 0);
    __syncthreads();
    MM(AEXPR_W, 0);
#pragma unroll
    for (int mt = 0; mt < 2; ++mt)
#pragma unroll
      for (int nt = 0; nt < 4; ++nt)
#pragma unroll
        for (int r = 0; r < 4; ++r)
          v_[mt][nt * 4 + r] -= 0.005f * acc[mt][nt][r];
  }

  // ---- store (2, 16384, 256) fp32 ----
#pragma unroll
  for (int mt = 0; mt < 2; ++mt) {
    float* ozp = out + (mrow + mt * 16) * 256 + nq * 64 + g * 4;
    float* ovp = ozp + 16384 * 256;
#pragma unroll
    for (int t = 0; t < 4; ++t) {
      float4 a, b;
      a.x = z_[mt][t * 4 + 0]; a.y = z_[mt][t * 4 + 1];
      a.z = z_[mt][t * 4 + 2]; a.w = z_[mt][t * 4 + 3];
      b.x = v_[mt][t * 4 + 0]; b.y = v_[mt][t * 4 + 1];
      b.z = v_[mt][t * 4 + 2]; b.w = v_[mt][t * 4 + 3];
      *reinterpret_cast<float4*>(ozp + t * 16) = a;
      *reinterpret_cast<float4*>(ovp + t * 16) = b;
    }
  }
}

extern "C" void kernel_launch(void* const* d_in, const int* in_sizes, int n_in,
                              void* d_out, int out_size, void* d_ws,
                              size_t ws_size, hipStream_t stream) {
  (void)in_sizes; (void)n_in; (void)d_ws; (void)ws_size; (void)out_size;
  const float* z0 = (const float*)d_in[0];
  const float* v0 = (const float*)d_in[1];
  const float* Wg = (const float*)d_in[2];
  const float* bg = (const float*)d_in[3];
  float* out = (float*)d_out;
  rhmc_kernel<<<256, 512, 0, stream>>>(z0, v0, Wg, bg, out);
}